// Round 12
// baseline (141.032 us; speedup 1.0000x reference)
//
#include <hip/hip_runtime.h>

// Bahdanau attention. query [8][400][256], y [8][400][256], Wq_w [128][256],
// Wq_b [128], Wy_w [128][256], Wy_b [128], v_w [1][128], v_b (dropped:
// softmax shift-invariant), n_wins_y [8] i32. out [8][400][256] f32.
//
// score = sum_a v_a*tanh(qp+yp) ~ const + sum_a (-2 v_a)/(Eq_a*Ey_a + 1),
// Eq = e^{2 qp}, Ey = e^{2 yp} precomputed (1 fma/elem + 1 rcp/4).
//
// Lesson stack:
//  R4:  no runtime-indexed register arrays (scratch spill).
//  R7:  no lane-scattered global reads (W transposed in K0).
//  R10: broadcast loads scalarize ONLY if workgroup-uniform (blockIdx/loop).
//  R11: uniform s_loads worked BUT compiler starved VGPRs (24/32) and lost
//       blocking/ILP in proj+apply. R12: proj reverted to proven R9 LDS form;
//       score keeps per-thread state in 8 named accs (lane=t, q in uniform
//       8-unrolled loop w/ SGPR eq); apply keeps p in softmax wave's own regs
//       and broadcasts via v_readlane -> SGPR fma operand. Zero LDS/barriers
//       in score & apply.

#define LOG2E 1.4426950408889634f
#define TANH_SCALE 2.8853900817779268f  // 2*log2(e)

constexpr int TQn = 400, TYn = 400, AD = 128, DD = 256;

// ---------------- K0: WT4[k4][a] = W[a][4k4..4k4+3]; vneg = -2v ------------
__global__ __launch_bounds__(128) void transpose_kernel(
    const float* __restrict__ Wq, const float* __restrict__ Wy,
    const float* __restrict__ vw,
    float4* __restrict__ WTq, float4* __restrict__ WTy,
    float* __restrict__ vneg)
{
    const int k4 = blockIdx.x & 63;
    const bool isq = blockIdx.x < 64;
    const float4* src = reinterpret_cast<const float4*>(isq ? Wq : Wy);
    float4* dst = isq ? WTq : WTy;
    const int a = threadIdx.x;                 // 0..127
    dst[k4 * 128 + a] = src[a * 64 + k4];
    if (blockIdx.x == 0) vneg[a] = -2.f * vw[a];
}

// ---------------- K1: proj (R9-proven) -> EqS packed / EyT transposed ------
// EqS[qgrp 400][a4 32][q 8][4] ; EyT[a4 32][3200 rows][4]
__global__ __launch_bounds__(256, 4) void proj_kernel(
    const float* __restrict__ qin, const float* __restrict__ yin,
    const float4* __restrict__ WTq, const float* __restrict__ bq,
    const float4* __restrict__ WTy, const float* __restrict__ by,
    float* __restrict__ EqS, float* __restrict__ EyT)
{
    const int blk = blockIdx.x;               // [0,400) q, [400,800) y
    const bool is_q = blk < 400;
    const int row0 = (is_q ? blk : blk - 400) * 8;   // global row (b folded)
    const float* in   = (is_q ? qin : yin) + (size_t)row0 * DD;
    const float4* wt  = is_q ? WTq : WTy;     // [64 k4][128 a]
    const float* bias = is_q ? bq : by;

    __shared__ float lin[8 * DD];             // 8 KB
    __shared__ float red[8][AD];              // 4 KB
    {
        const float4* in4 = reinterpret_cast<const float4*>(in);
        float4* l4s = reinterpret_cast<float4*>(lin);
        l4s[threadIdx.x]       = in4[threadIdx.x];
        l4s[threadIdx.x + 256] = in4[threadIdx.x + 256];
    }
    __syncthreads();

    const int a = threadIdx.x & 127;
    const int h = threadIdx.x >> 7;           // k-half
    float acc[8] = {0.f,0.f,0.f,0.f,0.f,0.f,0.f,0.f};
    const float4* l4 = reinterpret_cast<const float4*>(lin);
    #pragma unroll 8
    for (int i = 0; i < 32; ++i) {
        const int k4 = h * 32 + i;
        float4 w4 = wt[k4 * 128 + a];         // coalesced 16B/lane
        #pragma unroll
        for (int r = 0; r < 8; ++r) {
            float4 v = l4[r * 64 + k4];       // LDS broadcast
            acc[r] = fmaf(w4.x, v.x, acc[r]);
            acc[r] = fmaf(w4.y, v.y, acc[r]);
            acc[r] = fmaf(w4.z, v.z, acc[r]);
            acc[r] = fmaf(w4.w, v.w, acc[r]);
        }
    }
    if (h) {
        #pragma unroll
        for (int r = 0; r < 8; ++r) red[r][a] = acc[r];
    }
    __syncthreads();
    if (!h) {
        const float bb = bias[a];
        const int a4 = a >> 2, ac = a & 3;
        #pragma unroll
        for (int r = 0; r < 8; ++r) {
            const float e = __builtin_amdgcn_exp2f(
                (acc[r] + red[r][a] + bb) * TANH_SCALE);
            if (is_q)  // qgrp = row0/8 (block-aligned)
                EqS[(size_t)(row0 >> 3) * 1024 + a4 * 32 + r * 4 + ac] = e;
            else       // row = b*400 + t = row0 + r
                EyT[(size_t)a4 * 12800 + (size_t)(row0 + r) * 4 + ac] = e;
        }
    }
}

// ---------------- K2: raw scores; zero LDS, zero barriers ------------------
// block = (b, qg8); lane = t (448 thr = 7 waves); q = uniform unrolled loop,
// eq/vneg via scalar loads (uniform addrs).
__global__ __launch_bounds__(448, 2) void score_kernel(
    const float* __restrict__ EqS,   // [400][32][8][4]
    const float4* __restrict__ EyT4, // [32][3200]
    const float* __restrict__ vneg,  // [128] = -2v
    const int*  __restrict__ nwins,  // [B]
    float* __restrict__ s)           // [B][TQ][TY]
{
    const int grp = blockIdx.x;               // b*50 + qg
    const int b   = grp / 50;
    const int q0  = (grp % 50) * 8;
    const int n   = nwins[b];
    const int t   = threadIdx.x;              // 0..447
    if ((t & ~63) >= n) return;               // wave-uniform early exit

    const int ycol = b * TYn + min(t, TYn - 1);
    const float4* eqg = reinterpret_cast<const float4*>(EqS) + (size_t)grp * 256;
    const float4* vn4 = reinterpret_cast<const float4*>(vneg);

    float ac0 = 0.f, ac1 = 0.f, ac2 = 0.f, ac3 = 0.f;
    float ac4 = 0.f, ac5 = 0.f, ac6 = 0.f, ac7 = 0.f;
    for (int a4 = 0; a4 < 32; ++a4) {
        const float4 ey = EyT4[(size_t)a4 * 3200 + ycol];  // coalesced 1KB
        const float4* eqa = eqg + a4 * 8;                  // uniform -> s_load
        const float4 vv = vn4[a4];                         // uniform -> s_load
        const float4 e0 = eqa[0], e1 = eqa[1], e2 = eqa[2], e3 = eqa[3];
        const float4 e4 = eqa[4], e5 = eqa[5], e6 = eqa[6], e7 = eqa[7];
        #define SCORE_Q(ACC, EQ)                                            \
        {                                                                   \
            float a0 = fmaf(EQ.x, ey.x, 1.f);                               \
            float a1 = fmaf(EQ.y, ey.y, 1.f);                               \
            float a2 = fmaf(EQ.z, ey.z, 1.f);                               \
            float a3 = fmaf(EQ.w, ey.w, 1.f);                               \
            float p01 = a0 * a1, p23 = a2 * a3;                             \
            float R = __builtin_amdgcn_rcpf(p01 * p23);                     \
            float u = p23 * R, w = p01 * R;                                 \
            ACC = fmaf(vv.x, a1 * u, ACC);                                  \
            ACC = fmaf(vv.y, a0 * u, ACC);                                  \
            ACC = fmaf(vv.z, a3 * w, ACC);                                  \
            ACC = fmaf(vv.w, a2 * w, ACC);                                  \
        }
        SCORE_Q(ac0, e0) SCORE_Q(ac1, e1) SCORE_Q(ac2, e2) SCORE_Q(ac3, e3)
        SCORE_Q(ac4, e4) SCORE_Q(ac5, e5) SCORE_Q(ac6, e6) SCORE_Q(ac7, e7)
        #undef SCORE_Q
    }
    if (t < n) {
        float* srow = s + (size_t)(b * TQn + q0) * TYn + t;
        srow[0 * TYn] = ac0; srow[1 * TYn] = ac1;
        srow[2 * TYn] = ac2; srow[3 * TYn] = ac3;
        srow[4 * TYn] = ac4; srow[5 * TYn] = ac5;
        srow[6 * TYn] = ac6; srow[7 * TYn] = ac7;
    }
}

// ---------------- K3: softmax + att@y; wave=q, p stays in-regs -------------
// Zero LDS, zero barriers. Phase 2: lane=d4; p[t] via v_readlane (SGPR fma op).
__global__ __launch_bounds__(512, 2) void apply_kernel(
    const float* __restrict__ y,    // [B][TY][DD]
    const float* __restrict__ s,    // [B][TQ][TY]
    const int*  __restrict__ nwins, // [B]
    float* __restrict__ out)        // [B][TQ][DD]
{
    const int bid = blockIdx.x;               // b*50 + qg
    const int b   = bid / 50;
    const int q0  = (bid % 50) * 8;
    const int tid = threadIdx.x, wave = tid >> 6, lane = tid & 63;
    const int n = nwins[b];
    const float NEG_INF = -__builtin_inff();

    // ---- softmax for q = q0 + wave ----
    const float* srow = s + (size_t)(b * TQn + q0 + wave) * TYn;
    float sc0, sc1, sc2, sc3, sc4, sc5, sc6;
    {
        int t;
        t = 0 * 64 + lane; sc0 = (t < n) ? srow[t] : NEG_INF;
        t = 1 * 64 + lane; sc1 = (t < n) ? srow[t] : NEG_INF;
        t = 2 * 64 + lane; sc2 = (t < n) ? srow[t] : NEG_INF;
        t = 3 * 64 + lane; sc3 = (t < n) ? srow[t] : NEG_INF;
        t = 4 * 64 + lane; sc4 = (t < n) ? srow[t] : NEG_INF;
        t = 5 * 64 + lane; sc5 = (t < n) ? srow[t] : NEG_INF;
        t = 6 * 64 + lane; sc6 = (t < n) ? srow[t] : NEG_INF;
    }
    float m = fmaxf(fmaxf(fmaxf(sc0, sc1), fmaxf(sc2, sc3)),
                    fmaxf(fmaxf(sc4, sc5), sc6));
    #pragma unroll
    for (int off = 32; off >= 1; off >>= 1) m = fmaxf(m, __shfl_xor(m, off, 64));
    sc0 = __builtin_amdgcn_exp2f((sc0 - m) * LOG2E);
    sc1 = __builtin_amdgcn_exp2f((sc1 - m) * LOG2E);
    sc2 = __builtin_amdgcn_exp2f((sc2 - m) * LOG2E);
    sc3 = __builtin_amdgcn_exp2f((sc3 - m) * LOG2E);
    sc4 = __builtin_amdgcn_exp2f((sc4 - m) * LOG2E);
    sc5 = __builtin_amdgcn_exp2f((sc5 - m) * LOG2E);
    sc6 = __builtin_amdgcn_exp2f((sc6 - m) * LOG2E);
    float l = ((sc0 + sc1) + (sc2 + sc3)) + ((sc4 + sc5) + sc6);
    #pragma unroll
    for (int off = 32; off >= 1; off >>= 1) l += __shfl_xor(l, off, 64);
    const float inv = 1.0f / l;
    sc0 *= inv; sc1 *= inv; sc2 *= inv; sc3 *= inv;
    sc4 *= inv; sc5 *= inv; sc6 *= inv;

    // ---- apply: lane = d4 column; p broadcast from own-wave regs ----
    const float4* yb4 = reinterpret_cast<const float4*>(y) + (size_t)(b * TYn) * 64;
    float4 acc = {0.f, 0.f, 0.f, 0.f};
    #define CHUNK(J, SCJ)                                                   \
    {                                                                       \
        const int tb = (J) * 64;                                            \
        if (tb < n) {                                                       \
            const int te = min(64, n - tb);                                 \
            _Pragma("unroll 4")                                             \
            for (int tt = 0; tt < te; ++tt) {                               \
                const float ps = __int_as_float(__builtin_amdgcn_readlane(  \
                    __float_as_int(SCJ), tt));                              \
                const float4 yv = yb4[(size_t)(tb + tt) * 64 + lane];       \
                acc.x = fmaf(ps, yv.x, acc.x);                              \
                acc.y = fmaf(ps, yv.y, acc.y);                              \
                acc.z = fmaf(ps, yv.z, acc.z);                              \
                acc.w = fmaf(ps, yv.w, acc.w);                              \
            }                                                               \
        }                                                                   \
    }
    CHUNK(0, sc0) CHUNK(1, sc1) CHUNK(2, sc2) CHUNK(3, sc3)
    CHUNK(4, sc4) CHUNK(5, sc5) CHUNK(6, sc6)
    #undef CHUNK
    reinterpret_cast<float4*>(out)[(size_t)(b * TQn + q0 + wave) * 64 + lane] = acc;
}

extern "C" void kernel_launch(void* const* d_in, const int* in_sizes, int n_in,
                              void* d_out, int out_size, void* d_ws, size_t ws_size,
                              hipStream_t stream) {
    const float* query = (const float*)d_in[0];
    const float* y     = (const float*)d_in[1];
    const float* Wq_w  = (const float*)d_in[2];
    const float* Wq_b  = (const float*)d_in[3];
    const float* Wy_w  = (const float*)d_in[4];
    const float* Wy_b  = (const float*)d_in[5];
    const float* v_w   = (const float*)d_in[6];
    // d_in[7] = v_b: softmax-invariant, dropped.
    const int* nw      = (const int*)d_in[8];
    float* out = (float*)d_out;

    float4* WTq  = (float4*)d_ws;                    // 131 KB
    float4* WTy  = WTq + 64 * 128;                   // 131 KB
    float*  vneg = (float*)(WTy + 64 * 128);         // 512 B (pad 1 KB)
    float*  EqS  = vneg + 256;                       // [400][32][8][4] = 1.64 MB
    float*  EyT  = EqS + (size_t)400 * 1024;         // [32][3200][4]  = 1.64 MB
    float*  s    = EyT + (size_t)32 * 3200 * 4;      // [8][400][400]  = 5.12 MB

    transpose_kernel<<<128, 128, 0, stream>>>(Wq_w, Wy_w, v_w, WTq, WTy, vneg);
    proj_kernel<<<800, 256, 0, stream>>>(query, y, WTq, Wq_b, WTy, Wy_b, EqS, EyT);
    score_kernel<<<8 * 50, 448, 0, stream>>>(
        EqS, (const float4*)EyT, vneg, nw, s);
    apply_kernel<<<8 * 50, 512, 0, stream>>>(y, s, nw, out);
}

// Round 13
// 69.091 us; speedup vs baseline: 2.0413x; 2.0413x over previous
//
#include <hip/hip_runtime.h>

// Bahdanau attention. query [8][400][256], y [8][400][256], Wq_w [128][256],
// Wq_b [128], Wy_w [128][256], Wy_b [128], v_w [1][128], v_b (dropped:
// softmax shift-invariant), n_wins_y [8] i32. out [8][400][256] f32.
//
// score = sum_a v_a*tanh(qp+yp) ~ const + sum_a (-2 v_a)/(Eq_a*Ey_a + 1),
// Eq = e^{2 qp}, Ey = e^{2 yp} precomputed (1 fma/elem + 1 rcp/4).
//
// Lesson stack:
//  R4:  no runtime-indexed register arrays (scratch spill).
//  R7:  no lane-scattered global reads (W transposed in K0).
//  R10: broadcast loads scalarize ONLY if workgroup-uniform.
//  R11/R12: register-lean inner loops (uniform s_loads everywhere, readlane
//       broadcasts) make LLVM allocate 12-32 VGPRs and serialize all memory
//       latency. Keep explicit blocking + LDS staging so state stays live.
//  R13: best-of-breed assembly — R12 transpose/proj/score + R8 apply (dbuf
//       LDS y tiles, 4q/block), all previously measured/proven.

#define LOG2E 1.4426950408889634f
#define TANH_SCALE 2.8853900817779268f  // 2*log2(e)

constexpr int TQn = 400, TYn = 400, AD = 128, DD = 256;

// ---------------- K0: WT4[k4][a] = W[a][4k4..4k4+3]; vneg = -2v ------------
__global__ __launch_bounds__(128) void transpose_kernel(
    const float* __restrict__ Wq, const float* __restrict__ Wy,
    const float* __restrict__ vw,
    float4* __restrict__ WTq, float4* __restrict__ WTy,
    float* __restrict__ vneg)
{
    const int k4 = blockIdx.x & 63;
    const bool isq = blockIdx.x < 64;
    const float4* src = reinterpret_cast<const float4*>(isq ? Wq : Wy);
    float4* dst = isq ? WTq : WTy;
    const int a = threadIdx.x;                 // 0..127
    dst[k4 * 128 + a] = src[a * 64 + k4];
    if (blockIdx.x == 0) vneg[a] = -2.f * vw[a];
}

// ---------------- K1: proj (R9-proven) -> EqS packed / EyT transposed ------
// EqS[qgrp 400][a4 32][q 8][4] ; EyT[a4 32][3200 rows][4]
__global__ __launch_bounds__(256, 4) void proj_kernel(
    const float* __restrict__ qin, const float* __restrict__ yin,
    const float4* __restrict__ WTq, const float* __restrict__ bq,
    const float4* __restrict__ WTy, const float* __restrict__ by,
    float* __restrict__ EqS, float* __restrict__ EyT)
{
    const int blk = blockIdx.x;               // [0,400) q, [400,800) y
    const bool is_q = blk < 400;
    const int row0 = (is_q ? blk : blk - 400) * 8;   // global row (b folded)
    const float* in   = (is_q ? qin : yin) + (size_t)row0 * DD;
    const float4* wt  = is_q ? WTq : WTy;     // [64 k4][128 a]
    const float* bias = is_q ? bq : by;

    __shared__ float lin[8 * DD];             // 8 KB
    __shared__ float red[8][AD];              // 4 KB
    {
        const float4* in4 = reinterpret_cast<const float4*>(in);
        float4* l4s = reinterpret_cast<float4*>(lin);
        l4s[threadIdx.x]       = in4[threadIdx.x];
        l4s[threadIdx.x + 256] = in4[threadIdx.x + 256];
    }
    __syncthreads();

    const int a = threadIdx.x & 127;
    const int h = threadIdx.x >> 7;           // k-half
    float acc[8] = {0.f,0.f,0.f,0.f,0.f,0.f,0.f,0.f};
    const float4* l4 = reinterpret_cast<const float4*>(lin);
    #pragma unroll 8
    for (int i = 0; i < 32; ++i) {
        const int k4 = h * 32 + i;
        float4 w4 = wt[k4 * 128 + a];         // coalesced 16B/lane
        #pragma unroll
        for (int r = 0; r < 8; ++r) {
            float4 v = l4[r * 64 + k4];       // LDS broadcast
            acc[r] = fmaf(w4.x, v.x, acc[r]);
            acc[r] = fmaf(w4.y, v.y, acc[r]);
            acc[r] = fmaf(w4.z, v.z, acc[r]);
            acc[r] = fmaf(w4.w, v.w, acc[r]);
        }
    }
    if (h) {
        #pragma unroll
        for (int r = 0; r < 8; ++r) red[r][a] = acc[r];
    }
    __syncthreads();
    if (!h) {
        const float bb = bias[a];
        const int a4 = a >> 2, ac = a & 3;
        #pragma unroll
        for (int r = 0; r < 8; ++r) {
            const float e = __builtin_amdgcn_exp2f(
                (acc[r] + red[r][a] + bb) * TANH_SCALE);
            if (is_q)  // qgrp = row0/8 (block-aligned)
                EqS[(size_t)(row0 >> 3) * 1024 + a4 * 32 + r * 4 + ac] = e;
            else       // row = b*400 + t = row0 + r
                EyT[(size_t)a4 * 12800 + (size_t)(row0 + r) * 4 + ac] = e;
        }
    }
}

// ---------------- K2: raw scores; zero LDS, zero barriers ------------------
// block = (b, qg8); lane = t (448 thr = 7 waves); q = uniform unrolled loop,
// eq/vneg via scalar loads (uniform addrs).
__global__ __launch_bounds__(448, 2) void score_kernel(
    const float* __restrict__ EqS,   // [400][32][8][4]
    const float4* __restrict__ EyT4, // [32][3200]
    const float* __restrict__ vneg,  // [128] = -2v
    const int*  __restrict__ nwins,  // [B]
    float* __restrict__ s)           // [B][TQ][TY]
{
    const int grp = blockIdx.x;               // b*50 + qg
    const int b   = grp / 50;
    const int q0  = (grp % 50) * 8;
    const int n   = nwins[b];
    const int t   = threadIdx.x;              // 0..447
    if ((t & ~63) >= n) return;               // wave-uniform early exit

    const int ycol = b * TYn + min(t, TYn - 1);
    const float4* eqg = reinterpret_cast<const float4*>(EqS) + (size_t)grp * 256;
    const float4* vn4 = reinterpret_cast<const float4*>(vneg);

    float ac0 = 0.f, ac1 = 0.f, ac2 = 0.f, ac3 = 0.f;
    float ac4 = 0.f, ac5 = 0.f, ac6 = 0.f, ac7 = 0.f;
    for (int a4 = 0; a4 < 32; ++a4) {
        const float4 ey = EyT4[(size_t)a4 * 3200 + ycol];  // coalesced 1KB
        const float4* eqa = eqg + a4 * 8;                  // uniform -> s_load
        const float4 vv = vn4[a4];                         // uniform -> s_load
        const float4 e0 = eqa[0], e1 = eqa[1], e2 = eqa[2], e3 = eqa[3];
        const float4 e4 = eqa[4], e5 = eqa[5], e6 = eqa[6], e7 = eqa[7];
        #define SCORE_Q(ACC, EQ)                                            \
        {                                                                   \
            float a0 = fmaf(EQ.x, ey.x, 1.f);                               \
            float a1 = fmaf(EQ.y, ey.y, 1.f);                               \
            float a2 = fmaf(EQ.z, ey.z, 1.f);                               \
            float a3 = fmaf(EQ.w, ey.w, 1.f);                               \
            float p01 = a0 * a1, p23 = a2 * a3;                             \
            float R = __builtin_amdgcn_rcpf(p01 * p23);                     \
            float u = p23 * R, w = p01 * R;                                 \
            ACC = fmaf(vv.x, a1 * u, ACC);                                  \
            ACC = fmaf(vv.y, a0 * u, ACC);                                  \
            ACC = fmaf(vv.z, a3 * w, ACC);                                  \
            ACC = fmaf(vv.w, a2 * w, ACC);                                  \
        }
        SCORE_Q(ac0, e0) SCORE_Q(ac1, e1) SCORE_Q(ac2, e2) SCORE_Q(ac3, e3)
        SCORE_Q(ac4, e4) SCORE_Q(ac5, e5) SCORE_Q(ac6, e6) SCORE_Q(ac7, e7)
        #undef SCORE_Q
    }
    if (t < n) {
        float* srow = s + (size_t)(b * TQn + q0) * TYn + t;
        srow[0 * TYn] = ac0; srow[1 * TYn] = ac1;
        srow[2 * TYn] = ac2; srow[3 * TYn] = ac3;
        srow[4 * TYn] = ac4; srow[5 * TYn] = ac5;
        srow[6 * TYn] = ac6; srow[7 * TYn] = ac7;
    }
}

// ---------------- K3: softmax + att@y (R8-proven: 4q/block, dbuf y tiles) --
__global__ __launch_bounds__(256, 4) void apply_kernel(
    const float* __restrict__ y,    // [B][TY][DD]
    const float* __restrict__ s,    // [B][TQ][TY]
    const int*  __restrict__ nwins, // [B]
    float* __restrict__ out)        // [B][TQ][DD]
{
    const int bid = blockIdx.x;               // 8 * 100
    const int b   = bid / 100;
    const int q0  = (bid % 100) * 4;
    const int tid = threadIdx.x, wave = tid >> 6, lane = tid & 63;
    const int n = nwins[b];
    const float NEG_INF = -__builtin_inff();

    __shared__ float  s_p[4][408];            // 6.5 KB (p rows; 0 beyond n)
    __shared__ float4 s_y[2][16 * 64];        // 32 KB dbuf y tiles

    // prefetch y tile 0 early (overlaps softmax); rows 0..15 valid (n >= 200)
    const float4* yb = reinterpret_cast<const float4*>(y) + (size_t)(b * TYn) * 64;
    const int scol = tid & 63, srow0 = tid >> 6;   // staging coords (rows srow0+4k)
    float4 g0 = yb[(size_t)(srow0     ) * 64 + scol];
    float4 g1 = yb[(size_t)(srow0 +  4) * 64 + scol];
    float4 g2 = yb[(size_t)(srow0 +  8) * 64 + scol];
    float4 g3 = yb[(size_t)(srow0 + 12) * 64 + scol];

    // ---- softmax for q = q0 + wave (4 waves) ----
    const float* srow = s + (size_t)(b * TQn + q0 + wave) * TYn;
    float sc0, sc1, sc2, sc3, sc4, sc5, sc6;
    {
        int t;
        t = 0 * 64 + lane; sc0 = (t < n) ? srow[t] : NEG_INF;
        t = 1 * 64 + lane; sc1 = (t < n) ? srow[t] : NEG_INF;
        t = 2 * 64 + lane; sc2 = (t < n) ? srow[t] : NEG_INF;
        t = 3 * 64 + lane; sc3 = (t < n) ? srow[t] : NEG_INF;
        t = 4 * 64 + lane; sc4 = (t < n) ? srow[t] : NEG_INF;
        t = 5 * 64 + lane; sc5 = (t < n) ? srow[t] : NEG_INF;
        t = 6 * 64 + lane; sc6 = (t < n) ? srow[t] : NEG_INF;
    }
    float m = fmaxf(fmaxf(fmaxf(sc0, sc1), fmaxf(sc2, sc3)),
                    fmaxf(fmaxf(sc4, sc5), sc6));
    #pragma unroll
    for (int off = 32; off >= 1; off >>= 1) m = fmaxf(m, __shfl_xor(m, off, 64));
    sc0 = __builtin_amdgcn_exp2f((sc0 - m) * LOG2E);
    sc1 = __builtin_amdgcn_exp2f((sc1 - m) * LOG2E);
    sc2 = __builtin_amdgcn_exp2f((sc2 - m) * LOG2E);
    sc3 = __builtin_amdgcn_exp2f((sc3 - m) * LOG2E);
    sc4 = __builtin_amdgcn_exp2f((sc4 - m) * LOG2E);
    sc5 = __builtin_amdgcn_exp2f((sc5 - m) * LOG2E);
    sc6 = __builtin_amdgcn_exp2f((sc6 - m) * LOG2E);
    float l = ((sc0 + sc1) + (sc2 + sc3)) + ((sc4 + sc5) + sc6);
    #pragma unroll
    for (int off = 32; off >= 1; off >>= 1) l += __shfl_xor(l, off, 64);
    const float inv = 1.0f / l;
    s_p[wave][0 * 64 + lane] = sc0 * inv;
    s_p[wave][1 * 64 + lane] = sc1 * inv;
    s_p[wave][2 * 64 + lane] = sc2 * inv;
    s_p[wave][3 * 64 + lane] = sc3 * inv;
    s_p[wave][4 * 64 + lane] = sc4 * inv;
    s_p[wave][5 * 64 + lane] = sc5 * inv;
    {   // chunk 6: t up to 447 would overflow [408] -> guard (p beyond n unused)
        const int t = 6 * 64 + lane;
        if (t < TYn) s_p[wave][t] = sc6 * inv;
    }

    // ---- apply: wave = d4-group, lane = (q, d4i) -> 4-way broadcast reads ----
    const int q  = lane >> 4;                 // 0..3
    const int d4 = (wave << 4) | (lane & 15); // 0..63
    float4 acc = {0.f, 0.f, 0.f, 0.f};
    const int ntile = (n + 15) >> 4;          // 13..25, block-uniform

    __syncthreads();                          // s_p visible
    for (int i = 0; i < ntile; ++i) {
        float4* buf = s_y[i & 1];
        buf[(srow0     ) * 64 + scol] = g0;
        buf[(srow0 +  4) * 64 + scol] = g1;
        buf[(srow0 +  8) * 64 + scol] = g2;
        buf[(srow0 + 12) * 64 + scol] = g3;
        if (i + 1 < ntile) {
            const int t0n = (i + 1) * 16;     // rows <= 399 guaranteed
            g0 = yb[(size_t)(t0n + srow0     ) * 64 + scol];
            g1 = yb[(size_t)(t0n + srow0 +  4) * 64 + scol];
            g2 = yb[(size_t)(t0n + srow0 +  8) * 64 + scol];
            g3 = yb[(size_t)(t0n + srow0 + 12) * 64 + scol];
        }
        __syncthreads();  // buf ready; prior reads of this buf ended >=1 barrier ago
        const int tb = i * 16;
        #pragma unroll
        for (int ttl = 0; ttl < 16; ++ttl) {
            const float  pt = s_p[q][tb + ttl];     // 4 scalar broadcasts
            const float4 yv = buf[ttl * 64 + d4];   // 256B, 4-way broadcast
            acc.x = fmaf(pt, yv.x, acc.x);
            acc.y = fmaf(pt, yv.y, acc.y);
            acc.z = fmaf(pt, yv.z, acc.z);
            acc.w = fmaf(pt, yv.w, acc.w);
        }
    }
    reinterpret_cast<float4*>(out)[(size_t)(b * TQn + q0 + q) * 64 + d4] = acc;
}

extern "C" void kernel_launch(void* const* d_in, const int* in_sizes, int n_in,
                              void* d_out, int out_size, void* d_ws, size_t ws_size,
                              hipStream_t stream) {
    const float* query = (const float*)d_in[0];
    const float* y     = (const float*)d_in[1];
    const float* Wq_w  = (const float*)d_in[2];
    const float* Wq_b  = (const float*)d_in[3];
    const float* Wy_w  = (const float*)d_in[4];
    const float* Wy_b  = (const float*)d_in[5];
    const float* v_w   = (const float*)d_in[6];
    // d_in[7] = v_b: softmax-invariant, dropped.
    const int* nw      = (const int*)d_in[8];
    float* out = (float*)d_out;

    float4* WTq  = (float4*)d_ws;                    // 131 KB
    float4* WTy  = WTq + 64 * 128;                   // 131 KB
    float*  vneg = (float*)(WTy + 64 * 128);         // 512 B (pad 1 KB)
    float*  EqS  = vneg + 256;                       // [400][32][8][4] = 1.64 MB
    float*  EyT  = EqS + (size_t)400 * 1024;         // [32][3200][4]  = 1.64 MB
    float*  s    = EyT + (size_t)32 * 3200 * 4;      // [8][400][400]  = 5.12 MB

    transpose_kernel<<<128, 128, 0, stream>>>(Wq_w, Wy_w, v_w, WTq, WTy, vneg);
    proj_kernel<<<800, 256, 0, stream>>>(query, y, WTq, Wq_b, WTy, Wy_b, EqS, EyT);
    score_kernel<<<8 * 50, 448, 0, stream>>>(
        EqS, (const float4*)EyT, vneg, nw, s);
    apply_kernel<<<8 * 100, 256, 0, stream>>>(y, s, nw, out);
}

// Round 14
// 64.976 us; speedup vs baseline: 2.1705x; 1.0633x over previous
//
#include <hip/hip_runtime.h>

// Bahdanau attention. query [8][400][256], y [8][400][256], Wq_w [128][256],
// Wq_b [128], Wy_w [128][256], Wy_b [128], v_w [1][128], v_b (dropped:
// softmax shift-invariant), n_wins_y [8] i32. out [8][400][256] f32.
//
// score = sum_a v_a*tanh(qp+yp) ~ const + sum_a (-2 v_a)/(Eq_a*Ey_a + 1),
// Eq = e^{2 qp}, Ey = e^{2 yp} precomputed (1 fma/elem + 1 rcp/4).
//
// Lesson stack:
//  R4:  no runtime-indexed register arrays (scratch spill).
//  R7:  no lane-scattered global reads (W transposed in K0).
//  R10: broadcast loads scalarize ONLY if workgroup-uniform.
//  R11/R12: register-lean inner loops starve VGPRs & serialize latency; keep
//       explicit blocking + staging so state stays live.
//  R14: parallelism doubled where latency was exposed: proj 4 rows/block
//       (1600 blocks), score 4q/block (800 blocks, 5600 waves). Code shapes
//       unchanged from proven R12/R13 forms.

#define LOG2E 1.4426950408889634f
#define TANH_SCALE 2.8853900817779268f  // 2*log2(e)

constexpr int TQn = 400, TYn = 400, AD = 128, DD = 256;

// ---------------- K0: WT4[k4][a] = W[a][4k4..4k4+3]; vneg = -2v ------------
__global__ __launch_bounds__(128) void transpose_kernel(
    const float* __restrict__ Wq, const float* __restrict__ Wy,
    const float* __restrict__ vw,
    float4* __restrict__ WTq, float4* __restrict__ WTy,
    float* __restrict__ vneg)
{
    const int k4 = blockIdx.x & 63;
    const bool isq = blockIdx.x < 64;
    const float4* src = reinterpret_cast<const float4*>(isq ? Wq : Wy);
    float4* dst = isq ? WTq : WTy;
    const int a = threadIdx.x;                 // 0..127
    dst[k4 * 128 + a] = src[a * 64 + k4];
    if (blockIdx.x == 0) vneg[a] = -2.f * vw[a];
}

// ---------------- K1: proj -> EqS packed / EyT transposed ------------------
// 4 rows/block, 1600 blocks x 256 thr (a = tid&127, k-half = tid>>7).
// EqS[qgrp 400][a4 32][q 8][4] ; EyT[a4 32][3200 rows][4]
__global__ __launch_bounds__(256, 4) void proj_kernel(
    const float* __restrict__ qin, const float* __restrict__ yin,
    const float4* __restrict__ WTq, const float* __restrict__ bq,
    const float4* __restrict__ WTy, const float* __restrict__ by,
    float* __restrict__ EqS, float* __restrict__ EyT)
{
    const int blk = blockIdx.x;               // [0,800) q, [800,1600) y
    const bool is_q = blk < 800;
    const int row0 = (is_q ? blk : blk - 800) * 4;   // global row (b folded)
    const float* in   = (is_q ? qin : yin) + (size_t)row0 * DD;
    const float4* wt  = is_q ? WTq : WTy;     // [64 k4][128 a]
    const float* bias = is_q ? bq : by;

    __shared__ float lin[4 * DD];             // 4 KB
    __shared__ float red[4][AD];              // 2 KB
    {
        const float4* in4 = reinterpret_cast<const float4*>(in);
        reinterpret_cast<float4*>(lin)[threadIdx.x] = in4[threadIdx.x];  // 1/thread
    }
    __syncthreads();

    const int a = threadIdx.x & 127;
    const int h = threadIdx.x >> 7;           // k-half
    float acc[4] = {0.f, 0.f, 0.f, 0.f};
    const float4* l4 = reinterpret_cast<const float4*>(lin);
    #pragma unroll 8
    for (int i = 0; i < 32; ++i) {
        const int k4 = h * 32 + i;
        float4 w4 = wt[k4 * 128 + a];         // coalesced 16B/lane
        #pragma unroll
        for (int r = 0; r < 4; ++r) {
            float4 v = l4[r * 64 + k4];       // LDS broadcast (wave-uniform)
            acc[r] = fmaf(w4.x, v.x, acc[r]);
            acc[r] = fmaf(w4.y, v.y, acc[r]);
            acc[r] = fmaf(w4.z, v.z, acc[r]);
            acc[r] = fmaf(w4.w, v.w, acc[r]);
        }
    }
    if (h) {
        #pragma unroll
        for (int r = 0; r < 4; ++r) red[r][a] = acc[r];
    }
    __syncthreads();
    if (!h) {
        const float bb = bias[a];
        const int a4 = a >> 2, ac = a & 3;
        const int qoff = (row0 & 7);          // 0 or 4 within the 8q group
        #pragma unroll
        for (int r = 0; r < 4; ++r) {
            const float e = __builtin_amdgcn_exp2f(
                (acc[r] + red[r][a] + bb) * TANH_SCALE);
            if (is_q)
                EqS[(size_t)(row0 >> 3) * 1024 + a4 * 32 + (qoff + r) * 4 + ac] = e;
            else
                EyT[(size_t)a4 * 12800 + (size_t)(row0 + r) * 4 + ac] = e;
        }
    }
}

// ---------------- K2: raw scores; zero LDS, zero barriers; 4q/block --------
// block = (b, qg4); lane = t (448 thr = 7 waves); q = uniform unrolled loop,
// eq/vneg via scalar loads (uniform addrs).
__global__ __launch_bounds__(448, 2) void score_kernel(
    const float* __restrict__ EqS,   // [400 qgrp][32][8][4]
    const float4* __restrict__ EyT4, // [32][3200]
    const float* __restrict__ vneg,  // [128] = -2v
    const int*  __restrict__ nwins,  // [B]
    float* __restrict__ s)           // [B][TQ][TY]
{
    const int grp = blockIdx.x;               // b*100 + qg
    const int b   = grp / 100;
    const int qg  = grp % 100;
    const int q0  = qg * 4;
    const int n   = nwins[b];
    const int t   = threadIdx.x;              // 0..447
    if ((t & ~63) >= n) return;               // wave-uniform early exit

    const int ycol = b * TYn + min(t, TYn - 1);
    // 8q-group base + 4q half offset
    const float4* eqg = reinterpret_cast<const float4*>(EqS)
                      + (size_t)(b * 50 + (qg >> 1)) * 256 + 4 * (qg & 1);
    const float4* vn4 = reinterpret_cast<const float4*>(vneg);

    float ac0 = 0.f, ac1 = 0.f, ac2 = 0.f, ac3 = 0.f;
    for (int a4 = 0; a4 < 32; ++a4) {
        const float4 ey = EyT4[(size_t)a4 * 3200 + ycol];  // coalesced 1KB
        const float4* eqa = eqg + a4 * 8;                  // uniform -> s_load
        const float4 vv = vn4[a4];                         // uniform -> s_load
        const float4 e0 = eqa[0], e1 = eqa[1], e2 = eqa[2], e3 = eqa[3];
        #define SCORE_Q(ACC, EQ)                                            \
        {                                                                   \
            float a0 = fmaf(EQ.x, ey.x, 1.f);                               \
            float a1 = fmaf(EQ.y, ey.y, 1.f);                               \
            float a2 = fmaf(EQ.z, ey.z, 1.f);                               \
            float a3 = fmaf(EQ.w, ey.w, 1.f);                               \
            float p01 = a0 * a1, p23 = a2 * a3;                             \
            float R = __builtin_amdgcn_rcpf(p01 * p23);                     \
            float u = p23 * R, w = p01 * R;                                 \
            ACC = fmaf(vv.x, a1 * u, ACC);                                  \
            ACC = fmaf(vv.y, a0 * u, ACC);                                  \
            ACC = fmaf(vv.z, a3 * w, ACC);                                  \
            ACC = fmaf(vv.w, a2 * w, ACC);                                  \
        }
        SCORE_Q(ac0, e0) SCORE_Q(ac1, e1) SCORE_Q(ac2, e2) SCORE_Q(ac3, e3)
        #undef SCORE_Q
    }
    if (t < n) {
        float* srow = s + (size_t)(b * TQn + q0) * TYn + t;
        srow[0 * TYn] = ac0; srow[1 * TYn] = ac1;
        srow[2 * TYn] = ac2; srow[3 * TYn] = ac3;
    }
}

// ---------------- K3: softmax + att@y (R8-proven: 4q/block, dbuf y tiles) --
__global__ __launch_bounds__(256, 4) void apply_kernel(
    const float* __restrict__ y,    // [B][TY][DD]
    const float* __restrict__ s,    // [B][TQ][TY]
    const int*  __restrict__ nwins, // [B]
    float* __restrict__ out)        // [B][TQ][DD]
{
    const int bid = blockIdx.x;               // 8 * 100
    const int b   = bid / 100;
    const int q0  = (bid % 100) * 4;
    const int tid = threadIdx.x, wave = tid >> 6, lane = tid & 63;
    const int n = nwins[b];
    const float NEG_INF = -__builtin_inff();

    __shared__ float  s_p[4][408];            // 6.5 KB (p rows; 0 beyond n)
    __shared__ float4 s_y[2][16 * 64];        // 32 KB dbuf y tiles

    // prefetch y tile 0 early (overlaps softmax); rows 0..15 valid (n >= 200)
    const float4* yb = reinterpret_cast<const float4*>(y) + (size_t)(b * TYn) * 64;
    const int scol = tid & 63, srow0 = tid >> 6;   // staging coords (rows srow0+4k)
    float4 g0 = yb[(size_t)(srow0     ) * 64 + scol];
    float4 g1 = yb[(size_t)(srow0 +  4) * 64 + scol];
    float4 g2 = yb[(size_t)(srow0 +  8) * 64 + scol];
    float4 g3 = yb[(size_t)(srow0 + 12) * 64 + scol];

    // ---- softmax for q = q0 + wave (4 waves) ----
    const float* srow = s + (size_t)(b * TQn + q0 + wave) * TYn;
    float sc0, sc1, sc2, sc3, sc4, sc5, sc6;
    {
        int t;
        t = 0 * 64 + lane; sc0 = (t < n) ? srow[t] : NEG_INF;
        t = 1 * 64 + lane; sc1 = (t < n) ? srow[t] : NEG_INF;
        t = 2 * 64 + lane; sc2 = (t < n) ? srow[t] : NEG_INF;
        t = 3 * 64 + lane; sc3 = (t < n) ? srow[t] : NEG_INF;
        t = 4 * 64 + lane; sc4 = (t < n) ? srow[t] : NEG_INF;
        t = 5 * 64 + lane; sc5 = (t < n) ? srow[t] : NEG_INF;
        t = 6 * 64 + lane; sc6 = (t < n) ? srow[t] : NEG_INF;
    }
    float m = fmaxf(fmaxf(fmaxf(sc0, sc1), fmaxf(sc2, sc3)),
                    fmaxf(fmaxf(sc4, sc5), sc6));
    #pragma unroll
    for (int off = 32; off >= 1; off >>= 1) m = fmaxf(m, __shfl_xor(m, off, 64));
    sc0 = __builtin_amdgcn_exp2f((sc0 - m) * LOG2E);
    sc1 = __builtin_amdgcn_exp2f((sc1 - m) * LOG2E);
    sc2 = __builtin_amdgcn_exp2f((sc2 - m) * LOG2E);
    sc3 = __builtin_amdgcn_exp2f((sc3 - m) * LOG2E);
    sc4 = __builtin_amdgcn_exp2f((sc4 - m) * LOG2E);
    sc5 = __builtin_amdgcn_exp2f((sc5 - m) * LOG2E);
    sc6 = __builtin_amdgcn_exp2f((sc6 - m) * LOG2E);
    float l = ((sc0 + sc1) + (sc2 + sc3)) + ((sc4 + sc5) + sc6);
    #pragma unroll
    for (int off = 32; off >= 1; off >>= 1) l += __shfl_xor(l, off, 64);
    const float inv = 1.0f / l;
    s_p[wave][0 * 64 + lane] = sc0 * inv;
    s_p[wave][1 * 64 + lane] = sc1 * inv;
    s_p[wave][2 * 64 + lane] = sc2 * inv;
    s_p[wave][3 * 64 + lane] = sc3 * inv;
    s_p[wave][4 * 64 + lane] = sc4 * inv;
    s_p[wave][5 * 64 + lane] = sc5 * inv;
    {   // chunk 6: t up to 447 would overflow [408] -> guard (p beyond n unused)
        const int t = 6 * 64 + lane;
        if (t < TYn) s_p[wave][t] = sc6 * inv;
    }

    // ---- apply: wave = d4-group, lane = (q, d4i) -> 4-way broadcast reads ----
    const int q  = lane >> 4;                 // 0..3
    const int d4 = (wave << 4) | (lane & 15); // 0..63
    float4 acc = {0.f, 0.f, 0.f, 0.f};
    const int ntile = (n + 15) >> 4;          // 13..25, block-uniform

    __syncthreads();                          // s_p visible
    for (int i = 0; i < ntile; ++i) {
        float4* buf = s_y[i & 1];
        buf[(srow0     ) * 64 + scol] = g0;
        buf[(srow0 +  4) * 64 + scol] = g1;
        buf[(srow0 +  8) * 64 + scol] = g2;
        buf[(srow0 + 12) * 64 + scol] = g3;
        if (i + 1 < ntile) {
            const int t0n = (i + 1) * 16;     // rows <= 399 guaranteed
            g0 = yb[(size_t)(t0n + srow0     ) * 64 + scol];
            g1 = yb[(size_t)(t0n + srow0 +  4) * 64 + scol];
            g2 = yb[(size_t)(t0n + srow0 +  8) * 64 + scol];
            g3 = yb[(size_t)(t0n + srow0 + 12) * 64 + scol];
        }
        __syncthreads();  // buf ready; prior reads of this buf ended >=1 barrier ago
        const int tb = i * 16;
        #pragma unroll
        for (int ttl = 0; ttl < 16; ++ttl) {
            const float  pt = s_p[q][tb + ttl];     // 4 scalar broadcasts
            const float4 yv = buf[ttl * 64 + d4];   // 256B, 4-way broadcast
            acc.x = fmaf(pt, yv.x, acc.x);
            acc.y = fmaf(pt, yv.y, acc.y);
            acc.z = fmaf(pt, yv.z, acc.z);
            acc.w = fmaf(pt, yv.w, acc.w);
        }
    }
    reinterpret_cast<float4*>(out)[(size_t)(b * TQn + q0 + q) * 64 + d4] = acc;
}

extern "C" void kernel_launch(void* const* d_in, const int* in_sizes, int n_in,
                              void* d_out, int out_size, void* d_ws, size_t ws_size,
                              hipStream_t stream) {
    const float* query = (const float*)d_in[0];
    const float* y     = (const float*)d_in[1];
    const float* Wq_w  = (const float*)d_in[2];
    const float* Wq_b  = (const float*)d_in[3];
    const float* Wy_w  = (const float*)d_in[4];
    const float* Wy_b  = (const float*)d_in[5];
    const float* v_w   = (const float*)d_in[6];
    // d_in[7] = v_b: softmax-invariant, dropped.
    const int* nw      = (const int*)d_in[8];
    float* out = (float*)d_out;

    float4* WTq  = (float4*)d_ws;                    // 131 KB
    float4* WTy  = WTq + 64 * 128;                   // 131 KB
    float*  vneg = (float*)(WTy + 64 * 128);         // 512 B (pad 1 KB)
    float*  EqS  = vneg + 256;                       // [400][32][8][4] = 1.64 MB
    float*  EyT  = EqS + (size_t)400 * 1024;         // [32][3200][4]  = 1.64 MB
    float*  s    = EyT + (size_t)32 * 3200 * 4;      // [8][400][400]  = 5.12 MB

    transpose_kernel<<<128, 128, 0, stream>>>(Wq_w, Wy_w, v_w, WTq, WTy, vneg);
    proj_kernel<<<1600, 256, 0, stream>>>(query, y, WTq, Wq_b, WTy, Wy_b, EqS, EyT);
    score_kernel<<<8 * 100, 448, 0, stream>>>(
        EqS, (const float4*)EyT, vneg, nw, s);
    apply_kernel<<<8 * 100, 256, 0, stream>>>(y, s, nw, out);
}